// Round 4
// baseline (3659.279 us; speedup 1.0000x reference)
//
#include <hip/hip_runtime.h>
#include <hip/hip_bf16.h>
#include <cstdint>

#define NF_   4
#define NLOC_ 4096
#define NALL_ 4096
#define NNEI_ 128
#define RCUT_ 6.0f
#define RMIN_ 0.5f

// fast tanh via hardware exp + rcp: tanh(x) = 1 - 2/(exp(2x)+1)
// saturates correctly: exp(+inf)->inf -> 1 ; exp(-inf)->0 -> -1
__device__ __forceinline__ float fast_tanh(float x) {
    float e = __expf(2.0f * x);
    return 1.0f - 2.0f * __builtin_amdgcn_rcpf(e + 1.0f);
}

__device__ __forceinline__ unsigned pack_bf16(float a, float b) {
    unsigned short ua = __builtin_bit_cast(unsigned short, __float2bfloat16(a));
    unsigned short ub = __builtin_bit_cast(unsigned short, __float2bfloat16(b));
    return (unsigned)ua | ((unsigned)ub << 16);
}
__device__ __forceinline__ float bf16_lo(unsigned u) {
    return __builtin_bit_cast(float, u << 16);
}
__device__ __forceinline__ float bf16_hi(unsigned u) {
    return __builtin_bit_cast(float, u & 0xffff0000u);
}

// LDS budget: envs 2048 + Gs 6656 + Ts 1536 = 10240 B -> 15 blocks/CU -> 30 waves/CU
#define GQ_STRIDE 13   // uints per row; gcd(13,32)=1 -> conflict-free column reads

// One 24-channel quarter of layer 3 + fused T contraction.
// SKIPO must be a LITERAL (0 or 24) so h2[] stays statically indexed (rule #20:
// runtime-indexed per-thread arrays spill to scratch -> R3's 2.6 GB FETCH regression).
#define QUARTER(Q, SKIPO) do {                                                  \
    const int q_ = (Q);                                                         \
    const float* w3q = w3 + q_ * 24;                                            \
    const float* b3q = b3 + q_ * 24;                                            \
    float acc[24];                                                              \
    _Pragma("unroll") for (int m = 0; m < 24; ++m) acc[m] = b3q[m];             \
    _Pragma("unroll") for (int k = 0; k < 48; ++k) {                            \
        const float hk = h2[k];                                                 \
        _Pragma("unroll") for (int m = 0; m < 24; ++m)                          \
            acc[m] = fmaf(hk, w3q[k * 96 + m], acc[m]);                         \
    }                                                                           \
    __syncthreads();                                                            \
    _Pragma("unroll") for (int j = 0; j < 12; ++j) {                            \
        const float g0 = fast_tanh(acc[2 * j])     + h2[(SKIPO) + 2 * j];       \
        const float g1 = fast_tanh(acc[2 * j + 1]) + h2[(SKIPO) + 2 * j + 1];   \
        Gs[t * GQ_STRIDE + j] = pack_bf16(g0, g1);                              \
    }                                                                           \
    __syncthreads();                                                            \
    float t0 = 0.0f, t1 = 0.0f;                                                 \
    _Pragma("unroll 4") for (int n = noff; n < NNEI_; n += 2) {                 \
        const unsigned u = Gs[n * GQ_STRIDE + c];                               \
        const float ev = envs[n * 4 + d];                                       \
        t0 = fmaf(ev, bf16_lo(u), t0);                                          \
        t1 = fmaf(ev, bf16_hi(u), t1);                                          \
    }                                                                           \
    t0 += __shfl_down(t0, 12);                                                  \
    t1 += __shfl_down(t1, 12);                                                  \
    if (lg < 12) {                                                              \
        const int mg = q_ * 24 + 2 * c;                                         \
        Ts[d * 96 + mg]     = t0 * (1.0f / NNEI_);                              \
        Ts[d * 96 + mg + 1] = t1 * (1.0f / NNEI_);                              \
    }                                                                           \
} while (0)

__global__ __launch_bounds__(128, 8)
void descrpt_sea_kernel(
    const float* __restrict__ coord,
    const float* __restrict__ davg,
    const float* __restrict__ dstd,
    const float* __restrict__ w1, const float* __restrict__ b1,
    const float* __restrict__ w2, const float* __restrict__ b2,
    const float* __restrict__ w3, const float* __restrict__ b3,
    const int*   __restrict__ nlist,
    float* __restrict__ out)
{
    __shared__ float    envs[NNEI_ * 4];        // normalized env, [n][4]
    __shared__ unsigned Gs[NNEI_ * GQ_STRIDE];  // one 24-ch quarter of G, bf16x2-packed
    __shared__ float    Ts[4 * 96];             // T[d][m]

    const int t = threadIdx.x;             // neighbor slot
    const int a = blockIdx.x;              // atom id (f*NLOC + i)
    const int f = a >> 12;
    const int i = a & 4095;

    // ---- phase 1: environment matrix row for this neighbor ----
    const float* cf = coord + (size_t)f * (NALL_ * 3);
    const float cix = cf[i * 3 + 0];       // uniform -> scalar loads
    const float ciy = cf[i * 3 + 1];
    const float ciz = cf[i * 3 + 2];
    const int nb = nlist[(size_t)a * NNEI_ + t];
    float dx = cf[nb * 3 + 0] - cix;
    float dy = cf[nb * 3 + 1] - ciy;
    float dz = cf[nb * 3 + 2] - ciz;
    float r2 = fmaf(dx, dx, fmaf(dy, dy, dz * dz)) + 1e-12f;
    float r  = __builtin_amdgcn_sqrtf(r2);
    float rinv = __builtin_amdgcn_rcpf(r);
    float uu = (r - RMIN_) * (1.0f / (RCUT_ - RMIN_));
    float u2 = uu * uu;
    float mid = (uu * u2) * fmaf(-6.0f, u2, fmaf(15.0f, uu, -10.0f)) + 1.0f;
    float sw  = (r < RMIN_) ? 1.0f : ((r < RCUT_) ? mid : 0.0f);
    float sv  = sw * rinv;
    float e0 = sv;
    float e1 = sv * dx * rinv;
    float e2 = sv * dy * rinv;
    float e3 = sv * dz * rinv;
    const float4 da  = reinterpret_cast<const float4*>(davg)[t];
    const float4 dsd = reinterpret_cast<const float4*>(dstd)[t];
    e0 = (e0 - da.x) * __builtin_amdgcn_rcpf(dsd.x);
    e1 = (e1 - da.y) * __builtin_amdgcn_rcpf(dsd.y);
    e2 = (e2 - da.z) * __builtin_amdgcn_rcpf(dsd.z);
    e3 = (e3 - da.w) * __builtin_amdgcn_rcpf(dsd.w);
    envs[t * 4 + 0] = e0;
    envs[t * 4 + 1] = e1;
    envs[t * 4 + 2] = e2;
    envs[t * 4 + 3] = e3;

    // ---- phase 2: embedding MLP on x = env[...,0] ----
    const float x = e0;
    float h1[24];
#pragma unroll
    for (int j = 0; j < 24; ++j)
        h1[j] = fast_tanh(fmaf(x, w1[j], b1[j]));

    float h2[48];
    {
        float acc[48];
#pragma unroll
        for (int k = 0; k < 48; ++k) acc[k] = b2[k];
#pragma unroll
        for (int j = 0; j < 24; ++j) {
            const float hj = h1[j];
#pragma unroll
            for (int k = 0; k < 48; ++k)
                acc[k] = fmaf(hj, w2[j * 48 + k], acc[k]);
        }
#pragma unroll
        for (int k = 0; k < 48; ++k)
            h2[k] = fast_tanh(acc[k]) + h1[(k < 24) ? k : (k - 24)];
    }

    // contraction lane map (constant across quarters):
    // d = t>>5 (0..3); within 32-lane d-group: col c = lg%12, n-parity noff = lg/12
    const int lg   = t & 31;
    const int d    = t >> 5;
    const int c    = lg % 12;
    const int noff = lg / 12;   // 0,1 useful; 2 = spare lanes (harmless duplicates)

    // ---- phase 3: layer 3 in four 24-ch quarters, fused with T contraction ----
    // q-loop hand-unrolled by 2 so the resnet skip offset is a compile-time literal.
#pragma unroll 1
    for (int qh = 0; qh < 2; ++qh) {
        const int q0 = 2 * qh;
        QUARTER(q0,     0);
        QUARTER(q0 + 1, 24);
    }
    __syncthreads();

    // ---- phase 4: D[m][k] = sum_d T[d][m]*T[d][k], k < 8 ----
    float* outp = out + (size_t)a * 768;
#pragma unroll
    for (int qq = 0; qq < 6; ++qq) {
        const int idx = t + 128 * qq;      // 0..767
        const int m = idx >> 3;
        const int k = idx & 7;
        const float d0 = Ts[0 * 96 + m] * Ts[0 * 96 + k];
        const float d1 = Ts[1 * 96 + m] * Ts[1 * 96 + k];
        const float d2 = Ts[2 * 96 + m] * Ts[2 * 96 + k];
        const float d3 = Ts[3 * 96 + m] * Ts[3 * 96 + k];
        outp[idx] = (d0 + d1) + (d2 + d3);
    }
}

extern "C" void kernel_launch(void* const* d_in, const int* in_sizes, int n_in,
                              void* d_out, int out_size, void* d_ws, size_t ws_size,
                              hipStream_t stream) {
    const float* coord = (const float*)d_in[0];
    const float* davg  = (const float*)d_in[1];
    const float* dstd  = (const float*)d_in[2];
    const float* w1    = (const float*)d_in[3];
    const float* b1    = (const float*)d_in[4];
    const float* w2    = (const float*)d_in[5];
    const float* b2    = (const float*)d_in[6];
    const float* w3    = (const float*)d_in[7];
    const float* b3    = (const float*)d_in[8];
    const int*   nlist = (const int*)d_in[9];
    float* outp = (float*)d_out;

    descrpt_sea_kernel<<<dim3(NF_ * NLOC_), dim3(128), 0, stream>>>(
        coord, davg, dstd, w1, b1, w2, b2, w3, b3, nlist, outp);
}

// Round 5
// 315.661 us; speedup vs baseline: 11.5924x; 11.5924x over previous
//
#include <hip/hip_runtime.h>
#include <hip/hip_bf16.h>
#include <cstdint>

#define NF_   4
#define NLOC_ 4096
#define NALL_ 4096
#define NNEI_ 128
#define RCUT_ 6.0f
#define RMIN_ 0.5f

typedef __attribute__((ext_vector_type(8))) short    bhalf8;
typedef __attribute__((ext_vector_type(4))) float    f32x4;
typedef __attribute__((ext_vector_type(4))) unsigned u32x4;

// fast tanh via hardware exp + rcp: tanh(x) = 1 - 2/(exp(2x)+1); saturates correctly
__device__ __forceinline__ float fast_tanh(float x) {
    float e = __expf(2.0f * x);
    return 1.0f - 2.0f * __builtin_amdgcn_rcpf(e + 1.0f);
}
__device__ __forceinline__ unsigned short bfb(float v) {   // float -> bf16 bits (RNE)
    return __builtin_bit_cast(unsigned short, __float2bfloat16(v));
}
__device__ __forceinline__ float bff(unsigned short b) {   // bf16 bits -> float
    return __builtin_bit_cast(float, (unsigned)b << 16);
}
__device__ __forceinline__ unsigned pk(float a, float b) { // pack 2 bf16
    return (unsigned)bfb(a) | ((unsigned)bfb(b) << 16);
}

// LDS map (uint words), total 6400 words = 25600 B -> 6 blocks/CU:
//  [0,512)        envs  float[128][4]
//  [512,4864)     h2L   uint[128][34]  (bf16x2, K padded 48->64; dead after frag build)
//  [512,2624)     GsT   uint[32][66]   (OVERLAYS h2L; tanhY col-major, per-slab)
//  [4864,5248)    Th2L  float[2][4][48]
//  [5248,6016)    TyL   float[2][4][96]
//  [6016,6400)    Ts    float[4][96]
__global__ __launch_bounds__(128, 4)
void descrpt_sea_kernel(
    const float* __restrict__ coord,
    const float* __restrict__ davg,
    const float* __restrict__ dstd,
    const float* __restrict__ w1, const float* __restrict__ b1,
    const float* __restrict__ w2, const float* __restrict__ b2,
    const float* __restrict__ w3, const float* __restrict__ b3,
    const int*   __restrict__ nlist,
    float* __restrict__ out)
{
    __shared__ __align__(16) unsigned smem[6400];
    float*    envs = (float*)smem;
    unsigned* h2L  = smem + 512;
    unsigned* GsT  = smem + 512;            // overlay (h2L dead by first use)
    float*    Th2L = (float*)(smem + 4864);
    float*    TyL  = (float*)(smem + 5248);
    float*    Ts   = (float*)(smem + 6016);

    const int t = threadIdx.x;              // 0..127: neighbor slot / pair row
    const int a = blockIdx.x;               // atom id (f*NLOC + i)
    const int f = a >> 12;
    const int i = a & 4095;

    // ---- phase 1: environment matrix row for this neighbor ----
    const float* cf = coord + (size_t)f * (NALL_ * 3);
    const float cix = cf[i * 3 + 0];
    const float ciy = cf[i * 3 + 1];
    const float ciz = cf[i * 3 + 2];
    const int nbr = nlist[(size_t)a * NNEI_ + t];
    float dx = cf[nbr * 3 + 0] - cix;
    float dy = cf[nbr * 3 + 1] - ciy;
    float dz = cf[nbr * 3 + 2] - ciz;
    float r2 = fmaf(dx, dx, fmaf(dy, dy, dz * dz)) + 1e-12f;
    float r  = __builtin_amdgcn_sqrtf(r2);
    float rinv = __builtin_amdgcn_rcpf(r);
    float uu = (r - RMIN_) * (1.0f / (RCUT_ - RMIN_));
    float u2 = uu * uu;
    float mid = (uu * u2) * fmaf(-6.0f, u2, fmaf(15.0f, uu, -10.0f)) + 1.0f;
    float sw  = (r < RMIN_) ? 1.0f : ((r < RCUT_) ? mid : 0.0f);
    float sv  = sw * rinv;
    float e0 = sv;
    float e1 = sv * dx * rinv;
    float e2 = sv * dy * rinv;
    float e3 = sv * dz * rinv;
    const float4 da  = reinterpret_cast<const float4*>(davg)[t];
    const float4 dsd = reinterpret_cast<const float4*>(dstd)[t];
    e0 = (e0 - da.x) * __builtin_amdgcn_rcpf(dsd.x);
    e1 = (e1 - da.y) * __builtin_amdgcn_rcpf(dsd.y);
    e2 = (e2 - da.z) * __builtin_amdgcn_rcpf(dsd.z);
    e3 = (e3 - da.w) * __builtin_amdgcn_rcpf(dsd.w);
    envs[t * 4 + 0] = e0;
    envs[t * 4 + 1] = e1;
    envs[t * 4 + 2] = e2;
    envs[t * 4 + 3] = e3;

    // ---- phase 2: layers 1+2 per-lane (f32), h2 -> LDS bf16 ----
    {
        const float x = e0;
        float h1[24];
#pragma unroll
        for (int j = 0; j < 24; ++j)
            h1[j] = fast_tanh(fmaf(x, w1[j], b1[j]));

        float h2[48];
        {
            float acc2[48];
#pragma unroll
            for (int k = 0; k < 48; ++k) acc2[k] = b2[k];
#pragma unroll
            for (int j = 0; j < 24; ++j) {
                const float hj = h1[j];
#pragma unroll
                for (int k = 0; k < 48; ++k)
                    acc2[k] = fmaf(hj, w2[j * 48 + k], acc2[k]);
            }
#pragma unroll
            for (int k = 0; k < 48; ++k)
                h2[k] = fast_tanh(acc2[k]) + h1[(k < 24) ? k : (k - 24)];
        }
#pragma unroll
        for (int j = 0; j < 24; ++j)
            h2L[t * 34 + j] = pk(h2[2 * j], h2[2 * j + 1]);
#pragma unroll
        for (int j = 24; j < 34; ++j)
            h2L[t * 34 + j] = 0u;       // K pad 48->64
    }
    __syncthreads();   // B1: envs + h2L visible

    const int l   = t & 63;     // lane in wave
    const int w   = t >> 6;     // wave id (row half: rows 64w..64w+63)
    const int m16 = l & 15;     // 16x16 frag: A row / B,C col
    const int kg  = l >> 4;     // k-group 0..3

    // ---- envA fragments: A[m][k], rows 0-3 = env_hi[d], rows 4-7 = env_lo[d] ----
    bhalf8 envA[2];
#pragma unroll
    for (int ks = 0; ks < 2; ++ks) {
        bhalf8 av;
#pragma unroll
        for (int e = 0; e < 8; ++e) {
            const int row = 64 * w + 32 * ks + 8 * kg + e;   // pair index (K dim)
            const float v = envs[row * 4 + (m16 & 3)];
            const unsigned short hb = bfb(v);
            const unsigned short lb = bfb(v - bff(hb));
            const unsigned short sel = (m16 < 4) ? hb : ((m16 < 8) ? lb : (unsigned short)0);
            av[e] = (short)sel;
        }
        envA[ks] = av;
    }

    // ---- h2A fragments for layer-3 A-operand: 4 Mtiles x 2 Kslices (K=64 padded) ----
    bhalf8 h2A[4][2];
#pragma unroll
    for (int mt = 0; mt < 4; ++mt) {
#pragma unroll
        for (int ks = 0; ks < 2; ++ks) {
            const int row   = 64 * w + 16 * mt + m16;        // pair row
            const int wbase = row * 34 + 16 * ks + 4 * kg;   // uint idx (8B-aligned)
            const uint2 u01 = *(const uint2*)&h2L[wbase];
            const uint2 u23 = *(const uint2*)&h2L[wbase + 2];
            h2A[mt][ks] = __builtin_bit_cast(bhalf8, (u32x4){u01.x, u01.y, u23.x, u23.y});
        }
    }

    // ---- Th2 = env^T h2 partial (resnet folded into T): 3 Ntiles of 16 ----
#pragma unroll
    for (int nt = 0; nt < 3; ++nt) {
        f32x4 acc = {0.f, 0.f, 0.f, 0.f};
#pragma unroll
        for (int ks = 0; ks < 2; ++ks) {
            bhalf8 bv;
#pragma unroll
            for (int e = 0; e < 8; ++e) {
                const int row = 64 * w + 32 * ks + 8 * kg + e;
                const int col = 16 * nt + m16;               // h2 channel
                const unsigned u = h2L[row * 34 + (col >> 1)];
                const unsigned short bits = (col & 1) ? (unsigned short)(u >> 16)
                                                      : (unsigned short)(u & 0xffffu);
                bv[e] = (short)bits;
            }
            acc = __builtin_amdgcn_mfma_f32_16x16x32_bf16(envA[ks], bv, acc, 0, 0, 0);
        }
#pragma unroll
        for (int rgi = 0; rgi < 4; ++rgi) {
            const float v = acc[rgi] + __shfl_down(acc[rgi], 16);  // hi + lo rows
            if (kg == 0) Th2L[(w * 4 + rgi) * 48 + 16 * nt + m16] = v;
        }
    }
    __syncthreads();   // B2: h2L reads done before GsT overlay writes

    // ---- layer 3 + Ty contraction, 3 N-slabs of 32 cols ----
#pragma unroll 1
    for (int sb = 0; sb < 3; ++sb) {
        const int nbase = 32 * sb;
        f32x4 acc[4][2];
#pragma unroll
        for (int nt = 0; nt < 2; ++nt) {
            const float b3v = b3[nbase + 16 * nt + m16];     // bias via C-in (exact f32)
#pragma unroll
            for (int mt = 0; mt < 4; ++mt)
                acc[mt][nt] = (f32x4){b3v, b3v, b3v, b3v};
        }
#pragma unroll
        for (int ks = 0; ks < 2; ++ks) {
#pragma unroll
            for (int nt = 0; nt < 2; ++nt) {
                bhalf8 wb;
#pragma unroll
                for (int e = 0; e < 8; ++e) {
                    const int k  = 32 * ks + 8 * kg + e;     // channel (pad >=48 -> 0)
                    const int kc = (k < 48) ? k : 47;
                    const float wv = w3[kc * 96 + nbase + 16 * nt + m16];
                    wb[e] = (short)((k < 48) ? bfb(wv) : (unsigned short)0);
                }
#pragma unroll
                for (int mt = 0; mt < 4; ++mt)
                    acc[mt][nt] = __builtin_amdgcn_mfma_f32_16x16x32_bf16(
                        h2A[mt][ks], wb, acc[mt][nt], 0, 0, 0);
            }
        }
        // epilogue: tanhY -> GsT col-major bf16 pairs (resnet NOT added here)
#pragma unroll
        for (int mt = 0; mt < 4; ++mt) {
#pragma unroll
            for (int nt = 0; nt < 2; ++nt) {
                const int col  = 16 * nt + m16;              // slab-local col
                const int row0 = 64 * w + 16 * mt + 4 * kg;  // rows row0..row0+3
                const float g0 = fast_tanh(acc[mt][nt][0]);
                const float g1 = fast_tanh(acc[mt][nt][1]);
                const float g2 = fast_tanh(acc[mt][nt][2]);
                const float g3 = fast_tanh(acc[mt][nt][3]);
                GsT[col * 66 + (row0 >> 1)]     = pk(g0, g1);
                GsT[col * 66 + (row0 >> 1) + 1] = pk(g2, g3);
            }
        }
        __syncthreads();   // B3: GsT writes ordered before reads
        // Ty partial for this slab's 32 cols
#pragma unroll
        for (int nt = 0; nt < 2; ++nt) {
            f32x4 ty = {0.f, 0.f, 0.f, 0.f};
#pragma unroll
            for (int ks = 0; ks < 2; ++ks) {
                const int col = 16 * nt + m16;
                const int wb2 = col * 66 + 32 * w + 16 * ks + 4 * kg;
                const uint2 u01 = *(const uint2*)&GsT[wb2];
                const uint2 u23 = *(const uint2*)&GsT[wb2 + 2];
                const bhalf8 bg = __builtin_bit_cast(bhalf8, (u32x4){u01.x, u01.y, u23.x, u23.y});
                ty = __builtin_amdgcn_mfma_f32_16x16x32_bf16(envA[ks], bg, ty, 0, 0, 0);
            }
#pragma unroll
            for (int rgi = 0; rgi < 4; ++rgi) {
                const float v = ty[rgi] + __shfl_down(ty[rgi], 16);
                if (kg == 0) TyL[(w * 4 + rgi) * 96 + nbase + 16 * nt + m16] = v;
            }
        }
        __syncthreads();   // B4: WAR before next slab's GsT overwrite / final combine
    }

    // ---- combine partials: Ts[d][n] = (Ty + tile(Th2)) / NNEI ----
#pragma unroll
    for (int j = 0; j < 3; ++j) {
        const int idx = t + 128 * j;         // 0..383
        const int d   = idx / 96;
        const int n   = idx - 96 * d;
        const int c   = (n >= 48) ? (n - 48) : n;
        const float v = TyL[(0 * 4 + d) * 96 + n] + TyL[(1 * 4 + d) * 96 + n]
                      + Th2L[(0 * 4 + d) * 48 + c] + Th2L[(1 * 4 + d) * 48 + c];
        Ts[d * 96 + n] = v * (1.0f / NNEI_);
    }
    __syncthreads();   // B5

    // ---- phase 4: D[m][k] = sum_d T[d][m]*T[d][k], k < 8 ----
    float* outp = out + (size_t)a * 768;
#pragma unroll
    for (int qq = 0; qq < 6; ++qq) {
        const int idx = t + 128 * qq;        // 0..767
        const int m = idx >> 3;
        const int k = idx & 7;
        const float d0 = Ts[0 * 96 + m] * Ts[0 * 96 + k];
        const float d1 = Ts[1 * 96 + m] * Ts[1 * 96 + k];
        const float d2 = Ts[2 * 96 + m] * Ts[2 * 96 + k];
        const float d3 = Ts[3 * 96 + m] * Ts[3 * 96 + k];
        outp[idx] = (d0 + d1) + (d2 + d3);
    }
}

extern "C" void kernel_launch(void* const* d_in, const int* in_sizes, int n_in,
                              void* d_out, int out_size, void* d_ws, size_t ws_size,
                              hipStream_t stream) {
    const float* coord = (const float*)d_in[0];
    const float* davg  = (const float*)d_in[1];
    const float* dstd  = (const float*)d_in[2];
    const float* w1    = (const float*)d_in[3];
    const float* b1    = (const float*)d_in[4];
    const float* w2    = (const float*)d_in[5];
    const float* b2    = (const float*)d_in[6];
    const float* w3    = (const float*)d_in[7];
    const float* b3    = (const float*)d_in[8];
    const int*   nlist = (const int*)d_in[9];
    float* outp = (float*)d_out;

    descrpt_sea_kernel<<<dim3(NF_ * NLOC_), dim3(128), 0, stream>>>(
        coord, davg, dstd, w1, b1, w2, b2, w3, b3, nlist, outp);
}